// Round 5
// baseline (130.457 us; speedup 1.0000x reference)
//
#include <hip/hip_runtime.h>

#define TOKENS 16384
#define DIM    256
#define NEMB   1024
#define KB2    512     // bf16 K per matrix: [hi 0..255 | lo 256..511]
#define BM     128     // token tile
#define BN     256     // embed tile
#define NSTEP  12      // 3-term split-GEMM: K=768 in steps of 64

typedef __attribute__((ext_vector_type(8))) short short8;
typedef __attribute__((ext_vector_type(4))) float f32x4;

__device__ __forceinline__ unsigned int fsort(float f) {
    unsigned int u = __float_as_uint(f);
    return (u & 0x80000000u) ? ~u : (u | 0x80000000u);
}
__device__ __forceinline__ unsigned short bf16_rn(float f) {
    unsigned int u = __float_as_uint(f);
    u += 0x7fff + ((u >> 16) & 1);
    return (unsigned short)(u >> 16);
}
__device__ __forceinline__ float bf16_to_f(unsigned short h) {
    unsigned int u = (unsigned int)h << 16;
    return __uint_as_float(u);
}

// ------- prep: split x,E into bf16 hi/lo; exact fp32 esq; init keys -------
__global__ __launch_bounds__(256) void prep_kernel(const float* __restrict__ x,
                                                   const float* __restrict__ E,
                                                   unsigned short* __restrict__ xbf,
                                                   unsigned short* __restrict__ ebf,
                                                   float* __restrict__ esq,
                                                   unsigned long long* __restrict__ keys) {
    const int tid = blockIdx.x * 256 + threadIdx.x;
    if (tid < TOKENS) keys[tid] = ~0ull;          // fold the memset node in here
    const int wave = tid >> 6;
    const int lane = threadIdx.x & 63;
    #pragma unroll 1
    for (int rr = 0; rr < 4; ++rr) {
        const int row = wave * 4 + rr;                       // 0..17407, wave-uniform
        const bool isE = row >= TOKENS;
        const float* src = isE ? (E + (size_t)(row - TOKENS) * DIM)
                               : (x + (size_t)row * DIM);
        const float4 v = reinterpret_cast<const float4*>(src)[lane];
        const float f[4] = {v.x, v.y, v.z, v.w};
        unsigned long long hv = 0, lv = 0;
        #pragma unroll
        for (int i = 0; i < 4; ++i) {
            const unsigned short h = bf16_rn(f[i]);
            const float r = f[i] - bf16_to_f(h);             // exact (Sterbenz)
            const unsigned short l = bf16_rn(r);
            hv |= (unsigned long long)h << (16 * i);
            lv |= (unsigned long long)l << (16 * i);
        }
        unsigned short* dst = isE ? (ebf + (size_t)(row - TOKENS) * KB2)
                                  : (xbf + (size_t)row * KB2);
        *reinterpret_cast<unsigned long long*>(dst + 4 * lane)       = hv;
        *reinterpret_cast<unsigned long long*>(dst + 256 + 4 * lane) = lv;
        if (isE) {
            float s = fmaf(v.x, v.x, fmaf(v.y, v.y, fmaf(v.z, v.z, v.w * v.w)));
            #pragma unroll
            for (int off = 32; off > 0; off >>= 1) s += __shfl_down(s, off);
            if (lane == 0) esq[row - TOKENS] = s;
        }
    }
}

// ------- MFMA split-GEMM + fused argmin, 128x256 tile, 2-phase dbuf -------
// grid 512, XCD-swizzled. 4 waves (2x2), wave tile 64x128 = 4x8 frags of
// 16x16x32 bf16 MFMA -> 12 ds_read_b128 per 32 MFMA.
__global__ __launch_bounds__(256) void vq_mfma(const unsigned short* __restrict__ xbf,
                                               const unsigned short* __restrict__ ebf,
                                               const float* __restrict__ esq,
                                               unsigned long long* __restrict__ keys) {
    __shared__ unsigned short ls[2][(BM + BN) * 64];   // 2 x 48KB double buffer

    const int t    = threadIdx.x;
    const int lane = t & 63;
    const int w    = t >> 6;             // wave 0..3
    const int wr   = w >> 1, wc = w & 1;
    // T1 XCD swizzle (512 % 8 == 0, bijective)
    const int bid  = (int)blockIdx.x;
    const int lb   = (bid & 7) * 64 + (bid >> 3);
    const int m0   = (lb & 127) * BM;
    const int n0   = (lb >> 7) * BN;

    f32x4 acc[4][8];
    #pragma unroll
    for (int i = 0; i < 4; ++i)
        #pragma unroll
        for (int j = 0; j < 8; ++j) acc[i][j] = (f32x4){0.f, 0.f, 0.f, 0.f};

    const int srow   = lane >> 3;                 // row within 8-row staging group
    const int schunk = (lane & 7) ^ srow;         // pre-swizzled 16B chunk of the 128B row

    // stage K-step s into buffer (A rows 0..127, B rows 128..383); 12 instrs/wave
    auto stage = [&](char* lbase, int s) {
        const int ksA = (s < 4) ? s : (s - 4);    // A: hi,hi,lo
        const int ksB = (s < 8) ? s : (s - 8);    // B: hi,lo,hi
        #pragma unroll
        for (int c = 0; c < 12; ++c) {
            const int rbase = w * 96 + c * 8;     // uniform 8-row group base
            const int r     = rbase + srow;
            const char* g = (rbase < 128)
                ? (const char*)(xbf + (size_t)(m0 + r) * KB2 + ksA * 64) + schunk * 16
                : (const char*)(ebf + (size_t)(n0 + r - BM) * KB2 + ksB * 64) + schunk * 16;
            __builtin_amdgcn_global_load_lds(
                (const __attribute__((address_space(1))) unsigned int*)g,
                (__attribute__((address_space(3))) unsigned int*)(lbase + rbase * 128),
                16, 0, 0);
        }
    };

    auto compute = [&](const char* lbase) {
        const int rA = lane & 15;
        const int g  = lane >> 4;
        #pragma unroll
        for (int kh = 0; kh < 2; ++kh) {
            short8 af[4], bfr[8];
            #pragma unroll
            for (int mf = 0; mf < 4; ++mf) {
                const int row = wr * 64 + mf * 16 + rA;
                const int ch  = (kh * 4 + g) ^ (row & 7);    // read-side un-swizzle
                af[mf] = *(const short8*)(lbase + row * 128 + ch * 16);
            }
            #pragma unroll
            for (int nf = 0; nf < 8; ++nf) {
                const int row = wc * 128 + nf * 16 + rA;
                const int ch  = (kh * 4 + g) ^ (row & 7);
                bfr[nf] = *(const short8*)(lbase + (BM + row) * 128 + ch * 16);
            }
            #pragma unroll
            for (int mf = 0; mf < 4; ++mf)
                #pragma unroll
                for (int nf = 0; nf < 8; ++nf)
                    acc[mf][nf] = __builtin_amdgcn_mfma_f32_16x16x32_bf16(
                        af[mf], bfr[nf], acc[mf][nf], 0, 0, 0);
        }
    };

    // 2-phase pipeline: issue next-tile loads BEFORE computing current tile.
    stage((char*)ls[0], 0);
    __syncthreads();
    #pragma unroll 1
    for (int sp = 0; sp < NSTEP; sp += 2) {
        stage((char*)ls[1], sp + 1);
        compute((char*)ls[0]);
        __syncthreads();
        if (sp < NSTEP - 2) stage((char*)ls[0], sp + 2);
        compute((char*)ls[1]);
        __syncthreads();
    }

    // fused argmin epilogue: d2 = esq[n] - 2*dot (x_sq const per token, dropped)
    const int gq = lane >> 4;    // C/D: col = lane&15, row = gq*4 + reg
    const int cl = lane & 15;
    float bd[4][4];
    int   bi[4][4];
    #pragma unroll
    for (int mf = 0; mf < 4; ++mf)
        #pragma unroll
        for (int j = 0; j < 4; ++j) { bd[mf][j] = 3.4e38f; bi[mf][j] = 0; }

    #pragma unroll
    for (int nf = 0; nf < 8; ++nf) {       // ascending n within lane
        const int n    = n0 + wc * 128 + nf * 16 + cl;
        const float eq = esq[n];
        #pragma unroll
        for (int mf = 0; mf < 4; ++mf)
            #pragma unroll
            for (int j = 0; j < 4; ++j) {
                const float d = fmaf(-2.f, acc[mf][nf][j], eq);
                if (d < bd[mf][j]) { bd[mf][j] = d; bi[mf][j] = n; }  // strict <
            }
    }

    #pragma unroll
    for (int off = 8; off >= 1; off >>= 1) {   // reduce across the 16 cl lanes
        #pragma unroll
        for (int mf = 0; mf < 4; ++mf)
            #pragma unroll
            for (int j = 0; j < 4; ++j) {
                const float od = __shfl_xor(bd[mf][j], off);
                const int   oi = __shfl_xor(bi[mf][j], off);
                if (od < bd[mf][j] || (od == bd[mf][j] && oi < bi[mf][j])) {
                    bd[mf][j] = od; bi[mf][j] = oi;
                }
            }
    }

    if (cl == 0) {
        #pragma unroll
        for (int mf = 0; mf < 4; ++mf)
            #pragma unroll
            for (int j = 0; j < 4; ++j) {
                const int row = m0 + wr * 64 + mf * 16 + gq * 4 + j;
                const unsigned long long key =
                    ((unsigned long long)fsort(bd[mf][j]) << 32) | (unsigned int)bi[mf][j];
                atomicMin(&keys[row], key);
            }
    }
}

// ------- merge + gather: out = E[idx] (|(x+q)-x - q| ~ 1e-6 << threshold) -------
__global__ __launch_bounds__(256) void vq_out(const float* __restrict__ E,
                                              const unsigned long long* __restrict__ keys,
                                              float* __restrict__ out) {
    const int wave = (blockIdx.x * 256 + threadIdx.x) >> 6;  // 0..4095
    const int lane = threadIdx.x & 63;
    const int r0   = wave * 4;
    int idx[4];
    #pragma unroll
    for (int i = 0; i < 4; ++i) idx[i] = (int)(keys[r0 + i] & 0xFFFFFFFFull);
    float4 ev[4];
    #pragma unroll
    for (int i = 0; i < 4; ++i)
        ev[i] = reinterpret_cast<const float4*>(E + (size_t)idx[i] * DIM)[lane];
    #pragma unroll
    for (int i = 0; i < 4; ++i)
        reinterpret_cast<float4*>(out + (size_t)(r0 + i) * DIM)[lane] = ev[i];
}

extern "C" void kernel_launch(void* const* d_in, const int* in_sizes, int n_in,
                              void* d_out, int out_size, void* d_ws, size_t ws_size,
                              hipStream_t stream) {
    const float* x = (const float*)d_in[0];    // [16,1024,256] fp32
    const float* E = (const float*)d_in[1];    // [1024,256] fp32
    float* out = (float*)d_out;

    // ws layout: keys 128KB | esq 4KB | ebf 1MB
    unsigned long long* keys = (unsigned long long*)d_ws;
    float* esq = (float*)((char*)d_ws + TOKENS * sizeof(unsigned long long));
    unsigned short* ebf = (unsigned short*)((char*)d_ws + TOKENS * 8 + 4096);
    // x split lives in d_out (exact size match); fully consumed by vq_mfma
    // before vq_out overwrites d_out with the result.
    unsigned short* xbf = (unsigned short*)d_out;

    prep_kernel<<<(TOKENS + NEMB) / 16, 256, 0, stream>>>(x, E, xbf, ebf, esq, keys);
    vq_mfma<<<512, 256, 0, stream>>>(xbf, ebf, esq, keys);
    vq_out<<<TOKENS / 16, 256, 0, stream>>>(E, keys, out);
}